// Round 2
// baseline (1423.579 us; speedup 1.0000x reference)
//
#include <hip/hip_runtime.h>

#define N_NODES 50000
#define N_PAD   50048   // 391*128, GEMM epilogue needs no row guards
#define N_EDGES 800000
#define N_GRAPHS 512
#define F_IN 256
#define F_H 128
#define F_CAT 256

// bucketed CSR build
#define BSHIFT 9
#define NB 98           // ceil(50000/512) buckets
#define CAP 10240       // edge capacity per bucket (mean 8163, 23 sigma slack)
#define EPB 3125        // edges per scatter block (256 blocks)

#define AGG_BLOCKS 2048 // agg1 persistent grid: 8 blocks/CU on 256 CUs
#define B_AGG2 64       // agg2 blocks per (branch,slice) pass; 8 passes -> 512 blocks
#define PSLICE (N_GRAPHS * 32)   // floats per partial slice (64 KB)

typedef __attribute__((ext_vector_type(8))) short short8;
typedef __attribute__((ext_vector_type(4))) float f32x4;
typedef unsigned int uint;
typedef unsigned short ushort;

static __device__ __forceinline__ ushort f2bf(float f) {
    uint u = __float_as_uint(f);
    u += 0x7FFF + ((u >> 16) & 1);  // RNE
    return (ushort)(u >> 16);
}
static __device__ __forceinline__ float bflo(uint v) { return __uint_as_float(v << 16); }
static __device__ __forceinline__ float bfhi(uint v) { return __uint_as_float(v & 0xFFFF0000u); }
static __device__ __forceinline__ float bfu(ushort v) { return __uint_as_float((uint)v << 16); }

// async global->LDS, 16B per lane; lds base must be wave-uniform
#define GLL(g, l) __builtin_amdgcn_global_load_lds( \
    (const __attribute__((address_space(1))) unsigned int*)(g), \
    (__attribute__((address_space(3))) unsigned int*)(l), 16, 0, 0)

// ---------------------------------------------------------------------------
// S1: bucket-scatter edges. gcur is RELATIVE (zero-initialized by memset).
__global__ __launch_bounds__(256) void csr_scatter_kernel(
        const int* __restrict__ ei, int* __restrict__ gcur,
        uint* __restrict__ ebuf_td, uint* __restrict__ ebuf_bu) {
    __shared__ int lcnt[256];   // [dir*128 + bucket]
    __shared__ int lbase[256];
    int tid = threadIdx.x;
    lcnt[tid] = 0;
    __syncthreads();
    int e0 = blockIdx.x * EPB;
    for (int k = tid; k < EPB; k += 256) {
        int i = e0 + k;
        int s = ei[i], d = ei[N_EDGES + i];
        atomicAdd(&lcnt[d >> BSHIFT], 1);
        atomicAdd(&lcnt[128 + (s >> BSHIFT)], 1);
    }
    __syncthreads();
    if (tid < 2 * NB) {
        int dir = tid / NB, b = tid % NB;
        int c = lcnt[dir * 128 + b];
        lbase[dir * 128 + b] = c ? atomicAdd(&gcur[dir * NB + b], c) : 0;
    }
    __syncthreads();
    lcnt[tid] = 0;
    __syncthreads();
    for (int k = tid; k < EPB; k += 256) {
        int i = e0 + k;
        int s = ei[i], d = ei[N_EDGES + i];
        int bd = d >> BSHIFT, bs = s >> BSHIFT;
        int p = atomicAdd(&lcnt[bd], 1) + lbase[bd];
        ebuf_td[(size_t)bd * CAP + p] = (uint)s | ((uint)(d & 511) << 16);
        int q = atomicAdd(&lcnt[128 + bs], 1) + lbase[128 + bs];
        ebuf_bu[(size_t)bs * CAP + q] = (uint)d | ((uint)(s & 511) << 16);
    }
}

// ---------------------------------------------------------------------------
// S2: per-(bucket,dir) CSR build; also emits deg (u16) + dinv (free here,
// the node histogram already exists). Bucket-local scatter window.
__global__ __launch_bounds__(256) void csr_build_kernel(
        const uint* __restrict__ ebuf_td, const uint* __restrict__ ebuf_bu,
        const int* __restrict__ gcur,
        int* off_td, int* off_bu, ushort* deg_td, ushort* deg_bu,
        float* dinv_td, float* dinv_bu, ushort* csr_td, ushort* csr_bu) {
    int b = blockIdx.x, dir = blockIdx.y;
    const uint* ebuf = dir ? ebuf_bu : ebuf_td;
    int* off     = dir ? off_bu : off_td;
    ushort* deg  = dir ? deg_bu : deg_td;
    float* dinv  = dir ? dinv_bu : dinv_td;
    ushort* csr  = dir ? csr_bu : csr_td;
    __shared__ int cntL[512], offL[512], sm[256];
    int tid = threadIdx.x;
    cntL[tid] = 0; cntL[tid + 256] = 0;
    __syncthreads();
    int rbeg = b * CAP;
    int rend = rbeg + gcur[dir * NB + b];
    for (int k = rbeg + tid; k < rend; k += 256)
        atomicAdd(&cntL[ebuf[k] >> 16], 1);
    __syncthreads();
    int a0 = cntL[tid * 2], a1 = cntL[tid * 2 + 1];
    int ps = a0 + a1;
    sm[tid] = ps;
    __syncthreads();
    for (int o = 1; o < 256; o <<= 1) {
        int u = (tid >= o) ? sm[tid - o] : 0;
        __syncthreads();
        sm[tid] += u;
        __syncthreads();
    }
    int excl = sm[tid] - ps;
    offL[tid * 2] = excl;
    offL[tid * 2 + 1] = excl + a0;
    __syncthreads();
    int nbase = b << BSHIFT;
#pragma unroll
    for (int j = 0; j < 2; j++) {
        int nloc = tid + j * 256;
        int n = nbase + nloc;
        if (n < N_NODES) {
            off[n] = rbeg + offL[nloc];
            int c = cntL[nloc];
            deg[n] = (ushort)c;
            dinv[n] = rsqrtf((float)c + 1.0f);
        }
    }
    // pad rows (only needed once; bucket NB-1, dir both cover [50000, N_PAD))
    if (b == NB - 1) {
        int n = N_NODES + tid;
        if (n < N_PAD) dinv[n] = 1.0f;
    }
    cntL[tid] = offL[tid];
    cntL[tid + 256] = offL[tid + 256];
    __syncthreads();
    for (int k = rbeg + tid; k < rend; k += 256) {
        uint e = ebuf[k];
        int slot = atomicAdd(&cntL[e >> 16], 1);
        csr[rbeg + slot] = (ushort)(e & 0xFFFF);
    }
}

// ---------------------------------------------------------------------------
// Bt1[n][k]; Wt2[k][c] with c in concat([bu, td]) order.
__global__ void prep_w_kernel(const float* __restrict__ td_W1, const float* __restrict__ bu_W1,
                              const float* __restrict__ td_W2, const float* __restrict__ bu_W2,
                              ushort* __restrict__ Bt1, ushort* __restrict__ Wt2) {
    int n = blockIdx.x;   // 0..255
    int k = threadIdx.x;  // 0..255
    float w1 = (n < F_H) ? td_W1[(size_t)k * F_H + n] : bu_W1[(size_t)k * F_H + (n - F_H)];
    Bt1[(size_t)n * 256 + k] = f2bf(w1);
    if (k < 128) {
        float w2 = (n < F_H) ? bu_W2[(size_t)k * F_H + n]
                             : td_W2[(size_t)k * F_H + (n - F_H)];
        Wt2[(size_t)k * 256 + n] = f2bf(w2);
    }
}

// ---------------------------------------------------------------------------
// MFMA GEMM (layer 1): A = x f32 (in-register bf16 convert), B via GLL,
// C = linb bf16 row-scaled by branch dinv. 128x128 tile, BK=32, 4 waves.
__global__ __launch_bounds__(256) void gemm_mfma(
        const float* __restrict__ x, const ushort* __restrict__ Bt,
        ushort* __restrict__ C,
        const float* __restrict__ dinv_td, const float* __restrict__ dinv_bu) {
    __shared__ __align__(16) ushort As[128 * 32];
    __shared__ __align__(16) ushort Bs[128 * 32];
    int tid = threadIdx.x;
    int wave = tid >> 6, lane = tid & 63, quad = lane >> 4, l16 = lane & 15;
    size_t bm = (size_t)blockIdx.x * 128;
    size_t bn = (size_t)blockIdx.y * 128;
    const float* dsel = blockIdx.y ? dinv_bu : dinv_td;

    f32x4 acc[2][8];
    const f32x4 z4 = {0.f, 0.f, 0.f, 0.f};
#pragma unroll
    for (int i = 0; i < 2; i++)
#pragma unroll
        for (int j = 0; j < 8; j++) acc[i][j] = z4;

    int ar = tid >> 3;          // 0..31
    int akq = (tid & 7) * 4;    // 0..28
    int cb0 = wave * 64;
    int cb1 = 256 + wave * 64;
    int c0 = cb0 + lane, c1 = cb1 + lane;
    int r0 = c0 >> 2, s0 = (c0 & 3) * 8;
    int r1 = c1 >> 2, s1 = (c1 & 3) * 8;
    const ushort* b0p = Bt + (bn + r0) * 256 + s0;
    const ushort* b1p = Bt + (bn + r1) * 256 + s1;
    ushort* lB0 = Bs + cb0 * 8;
    ushort* lB1 = Bs + cb1 * 8;

    for (int kb = 0; kb < 8; kb++) {
        int k0 = kb * 32;
        float4 av[4];
#pragma unroll
        for (int j = 0; j < 4; j++) {
            size_t grow = bm + ar + j * 32;
            if (grow < N_NODES)
                av[j] = *(const float4*)(x + grow * F_IN + k0 + akq);
            else
                av[j] = make_float4(0.f, 0.f, 0.f, 0.f);
        }
        __syncthreads();  // previous iter's fragment reads done
        GLL(b0p + k0, lB0);
        GLL(b1p + k0, lB1);
#pragma unroll
        for (int j = 0; j < 4; j++) {
            ushort4 u;
            u.x = f2bf(av[j].x); u.y = f2bf(av[j].y);
            u.z = f2bf(av[j].z); u.w = f2bf(av[j].w);
            *(ushort4*)(As + (ar + j * 32) * 32 + akq) = u;
        }
        __syncthreads();  // drains vmcnt + lgkm, tiles ready
        short8 af0 = *(const short8*)(As + (wave * 32 + l16) * 32 + quad * 8);
        short8 af1 = *(const short8*)(As + (wave * 32 + 16 + l16) * 32 + quad * 8);
#pragma unroll
        for (int ct = 0; ct < 8; ct++) {
            short8 bfr = *(const short8*)(Bs + (ct * 16 + l16) * 32 + quad * 8);
            acc[0][ct] = __builtin_amdgcn_mfma_f32_16x16x32_bf16(af0, bfr, acc[0][ct], 0, 0, 0);
            acc[1][ct] = __builtin_amdgcn_mfma_f32_16x16x32_bf16(af1, bfr, acc[1][ct], 0, 0, 0);
        }
    }
#pragma unroll
    for (int rt = 0; rt < 2; rt++) {
#pragma unroll
        for (int r = 0; r < 4; r++) {
            size_t row = bm + wave * 32 + rt * 16 + quad * 4 + r;
            float dv = dsel[row];
#pragma unroll
            for (int ct = 0; ct < 8; ct++) {
                C[row * 256 + bn + ct * 16 + l16] = f2bf(acc[rt][ct][r] * dv);
            }
        }
    }
}

// ---------------------------------------------------------------------------
// Wave-gather: 16 lanes per edge row (uint4 = 8 bf16 cols per lane),
// 4 edge slots (q = lane>>4) concurrently; unroll-4 -> 16 edges in flight.
static __device__ __forceinline__ void acc8(float a[8], uint4 v) {
    a[0] += bflo(v.x); a[1] += bfhi(v.x);
    a[2] += bflo(v.y); a[3] += bfhi(v.y);
    a[4] += bflo(v.z); a[5] += bfhi(v.z);
    a[6] += bflo(v.w); a[7] += bfhi(v.w);
}

static __device__ __forceinline__ void gather_node4(
        const ushort* __restrict__ base, const ushort* __restrict__ csr,
        int kb, int ke, int q, float a[8]) {
    int k = kb;
    for (; k + 16 <= ke; k += 16) {
        int i0 = csr[k + q],      i1 = csr[k + 4 + q];
        int i2 = csr[k + 8 + q],  i3 = csr[k + 12 + q];
        uint4 v0 = *(const uint4*)(base + (size_t)i0 * F_CAT);
        uint4 v1 = *(const uint4*)(base + (size_t)i1 * F_CAT);
        uint4 v2 = *(const uint4*)(base + (size_t)i2 * F_CAT);
        uint4 v3 = *(const uint4*)(base + (size_t)i3 * F_CAT);
        acc8(a, v0); acc8(a, v1); acc8(a, v2); acc8(a, v3);
    }
    for (; k + 4 <= ke; k += 4) {
        uint4 v = *(const uint4*)(base + (size_t)csr[k + q] * F_CAT);
        acc8(a, v);
    }
    if (k + q < ke) {
        uint4 v = *(const uint4*)(base + (size_t)csr[k + q] * F_CAT);
        acc8(a, v);
    }
}

// ---------------------------------------------------------------------------
// Layer-1 aggregation: persistent grid, CONTIGUOUS per-wave node chunks
// (graph/write locality). h1s[n] = relu(dn*(self+neigh) + b1) * dn.
__global__ __launch_bounds__(256, 8) void agg1_kernel(
        const ushort* __restrict__ linS, ushort* __restrict__ h1s,
        const ushort* __restrict__ csr_td, const int* __restrict__ off_td,
        const ushort* __restrict__ deg_td, const float* __restrict__ dinv_td,
        const ushort* __restrict__ csr_bu, const int* __restrict__ off_bu,
        const ushort* __restrict__ deg_bu, const float* __restrict__ dinv_bu,
        const float* __restrict__ b_td, const float* __restrict__ b_bu) {
    int lane = threadIdx.x & 63;
    int wid = blockIdx.x * 4 + (threadIdx.x >> 6);
    int br = wid & 1;           // branch fixed per wave
    int wq = wid >> 1;          // wave index within branch, 0..4095
    const int WPB = AGG_BLOCKS * 2;   // waves per branch
    int beg = (int)(((long long)wq * N_NODES) / WPB);
    int end = (int)(((long long)(wq + 1) * N_NODES) / WPB);
    const ushort* csr = br ? csr_bu : csr_td;
    const int* off    = br ? off_bu : off_td;
    const ushort* deg = br ? deg_bu : deg_td;
    const float* dinv = br ? dinv_bu : dinv_td;
    const float* bias = br ? b_bu : b_td;
    int q = lane >> 4, c = lane & 15;
    int col = br * F_H + c * 8;
    const ushort* base = linS + col;
    float bs[8];
#pragma unroll
    for (int j = 0; j < 8; j++) bs[j] = bias[c * 8 + j];

    for (int n = beg; n < end; ++n) {
        float a[8] = {0.f, 0.f, 0.f, 0.f, 0.f, 0.f, 0.f, 0.f};
        int kb = off[n];
        gather_node4(base, csr, kb, kb + deg[n], q, a);
#pragma unroll
        for (int u = 0; u < 8; u++) {
            a[u] += __shfl_xor(a[u], 16);
            a[u] += __shfl_xor(a[u], 32);
        }
        uint4 vs = *(const uint4*)(base + (size_t)n * F_CAT);  // self
        acc8(a, vs);
        float dn = dinv[n];
        if (q == 0) {
            float o[8];
#pragma unroll
            for (int u = 0; u < 8; u++) o[u] = fmaxf(a[u] * dn + bs[u], 0.f) * dn;
            uint4 pk;
            pk.x = (uint)f2bf(o[0]) | ((uint)f2bf(o[1]) << 16);
            pk.y = (uint)f2bf(o[2]) | ((uint)f2bf(o[3]) << 16);
            pk.z = (uint)f2bf(o[4]) | ((uint)f2bf(o[5]) << 16);
            pk.w = (uint)f2bf(o[6]) | ((uint)f2bf(o[7]) << 16);
            *(uint4*)(h1s + (size_t)n * F_CAT + col) = pk;
        }
    }
}

// ---------------------------------------------------------------------------
// Layer-2 + pool, SOURCE-MAJOR: pooled[batch[d]] += dinv[d]*h1s[s] per edge,
// plus self term dinv[n]*h1s[n]. h1s read is SEQUENTIAL (no random row gather).
// Per-block LDS accumulator: all 512 graphs x 32-col slice (64 KB).
// Grid: (B_AGG2, 8); pass = br*4+slice. No global atomics: private partials.
// TD branch iterates out-edge lists (csr_bu) with weight dinv_td[d];
// BU branch iterates csr_td with weight dinv_bu[s]. batch/dinv are L2-hot.
__global__ __launch_bounds__(256, 2) void agg2_pool_kernel(
        const ushort* __restrict__ h1s, float* __restrict__ partial,
        const int* __restrict__ batch,
        const ushort* __restrict__ csr_td, const int* __restrict__ off_td,
        const ushort* __restrict__ deg_td,
        const ushort* __restrict__ csr_bu, const int* __restrict__ off_bu,
        const ushort* __restrict__ deg_bu,
        const float* __restrict__ dinv_td, const float* __restrict__ dinv_bu) {
    __shared__ float acc[PSLICE];   // 512 graphs x 32 cols = 64 KB
    int tid = threadIdx.x;
    int pass = blockIdx.y;          // 0..7
    int br = pass >> 2;             // 0=td 1=bu
    int slice = pass & 3;
    int b = blockIdx.x;             // 0..B_AGG2-1
    for (int i = tid; i < PSLICE; i += 256) acc[i] = 0.f;
    __syncthreads();

    // criss-cross: TD uses out-edge structure (bu) + dinv_td weights
    const ushort* csr = br ? csr_td : csr_bu;
    const int* off    = br ? off_td : off_bu;
    const ushort* deg = br ? deg_td : deg_bu;
    const float* dv   = br ? dinv_bu : dinv_td;

    int lane = tid & 63, w = tid >> 6;
    int h = lane >> 5, c = lane & 31;
    int beg = (b * N_NODES) / B_AGG2, end = ((b + 1) * N_NODES) / B_AGG2;
    int coloff = br * F_H + slice * 32 + c;

    // 1-node lookahead pipeline: edge-id table + (batch,dinv) gathers for
    // node n+4 issue while node n's shfl+ds_add loop runs.
    int o_c = 0, dg_c = 0, gk_c = 0, gn_c = 0;
    float wk_c = 0.f, hv_c = 0.f, sw_c = 0.f;
    int n0 = beg + w;
    if (n0 < end) {
        o_c = off[n0]; dg_c = deg[n0];
        int dpre = (lane < dg_c) ? (int)csr[o_c + lane] : 0;
        gk_c = batch[dpre]; wk_c = dv[dpre];
        hv_c = bfu(h1s[(size_t)n0 * F_CAT + coloff]);
        gn_c = batch[n0]; sw_c = dv[n0];
    }
    for (int n = n0; n < end; n += 4) {
        int o = o_c, dg = dg_c, gk = gk_c, gn = gn_c;
        float wk = wk_c, hv = hv_c, sw = sw_c;
        int nn = n + 4;
        if (nn < end) {
            o_c = off[nn]; dg_c = deg[nn];
            int dpre = (lane < dg_c) ? (int)csr[o_c + lane] : 0;
            gk_c = batch[dpre]; wk_c = dv[dpre];
            hv_c = bfu(h1s[(size_t)nn * F_CAT + coloff]);
            gn_c = batch[nn]; sw_c = dv[nn];
        }
        if (h == 0) atomicAdd(&acc[gn * 32 + c], sw * hv);   // self term
        int m = dg < 64 ? dg : 64;
        for (int k = 0; k < m; k += 2) {
            int kk = k + h;                     // half0: edge k, half1: edge k+1
            int g = __shfl(gk, kk);
            float ww = __shfl(wk, kk);
            if (kk < m) atomicAdd(&acc[g * 32 + c], ww * hv);
        }
        for (int base2 = 64; base2 < dg; base2 += 64) {  // cold path (deg>64)
            int mm = dg - base2; if (mm > 64) mm = 64;
            int d2 = (lane < mm) ? (int)csr[o + base2 + lane] : 0;
            int gk2 = batch[d2]; float wk2 = dv[d2];
            for (int k = 0; k < mm; k += 2) {
                int kk = k + h;
                int g = __shfl(gk2, kk);
                float ww = __shfl(wk2, kk);
                if (kk < mm) atomicAdd(&acc[g * 32 + c], ww * hv);
            }
        }
    }
    __syncthreads();
    float* pp = partial + ((size_t)pass * B_AGG2 + b) * PSLICE;
    for (int i = tid; i < PSLICE; i += 256) pp[i] = acc[i];
}

// ---------------------------------------------------------------------------
// Head: row = 64-way reduce of partials, then z = row@W2 + cnt*b2 in
// concat([bu,td]) order, then MLP relu(z@pw1+pb1)@pw2+pb2. One block/graph.
__global__ __launch_bounds__(256) void head_kernel(
        const float* __restrict__ partial, const int* __restrict__ batch,
        const ushort* __restrict__ Wt2,
        const float* __restrict__ td_b2, const float* __restrict__ bu_b2,
        const float* __restrict__ pw1, const float* __restrict__ pb1,
        const float* __restrict__ pw2, const float* __restrict__ pb2,
        float* __restrict__ out) {
    int g = blockIdx.x;
    int tid = threadIdx.x;
    __shared__ float row[256], z[256], hid[256];
    // tid = br*128 + slice*32 + c  ->  pass p = br*4+slice, elem e = g*32+c
    int p = ((tid >> 7) << 2) | ((tid >> 5) & 3);
    int e = g * 32 + (tid & 31);
    const float* pp = partial + (size_t)p * B_AGG2 * PSLICE + e;
    float s = 0.f;
    for (int b2 = 0; b2 < B_AGG2; ++b2) s += pp[(size_t)b2 * PSLICE];
    row[tid] = s;
    int lo = 0, hi = N_NODES;
    while (lo < hi) { int m = (lo + hi) >> 1; if (batch[m] < g) lo = m + 1; else hi = m; }
    int start = lo;
    lo = start; hi = N_NODES;
    while (lo < hi) { int m = (lo + hi) >> 1; if (batch[m] < g + 1) lo = m + 1; else hi = m; }
    float cnt = (float)(lo - start);
    __syncthreads();
    const float* rsel = (tid < 128) ? (row + F_H) : row;
    float b2v = (tid < 128) ? bu_b2[tid] : td_b2[tid - F_H];
    float acc = cnt * b2v;
    for (int k = 0; k < F_H; k++) acc += rsel[k] * bfu(Wt2[(size_t)k * 256 + tid]);
    z[tid] = acc;
    __syncthreads();
    float hh = pb1[tid];
    for (int k = 0; k < 256; k++) hh += z[k] * pw1[(size_t)k * 256 + tid];
    hid[tid] = fmaxf(hh, 0.f);
    __syncthreads();
    if (tid < 128) {
        float o = pb2[tid];
        for (int k = 0; k < 256; k++) o += hid[k] * pw2[(size_t)k * 128 + tid];
        out[(size_t)g * 128 + tid] = o;
    }
}

// ---------------------------------------------------------------------------
extern "C" void kernel_launch(void* const* d_in, const int* in_sizes, int n_in,
                              void* d_out, int out_size, void* d_ws, size_t ws_size,
                              hipStream_t stream) {
    const float* x     = (const float*)d_in[0];
    const int*   ei    = (const int*)d_in[1];
    const int*   batch = (const int*)d_in[2];
    const float* td_W1 = (const float*)d_in[4];
    const float* td_b1 = (const float*)d_in[5];
    const float* td_W2 = (const float*)d_in[6];
    const float* td_b2 = (const float*)d_in[7];
    const float* bu_W1 = (const float*)d_in[8];
    const float* bu_b1 = (const float*)d_in[9];
    const float* bu_W2 = (const float*)d_in[10];
    const float* bu_b2 = (const float*)d_in[11];
    const float* pw1   = (const float*)d_in[12];
    const float* pb1   = (const float*)d_in[13];
    const float* pw2   = (const float*)d_in[14];
    const float* pb2   = (const float*)d_in[15];
    float* out = (float*)d_out;

    // ---- workspace carve ----
    char* p = (char*)d_ws;
    auto alloc = [&](size_t bytes) { void* r = (void*)p; p += (bytes + 255) & ~(size_t)255; return r; };
    int* gcur = (int*)alloc(1024);           // memset region (scatter cursors)
    uint* ebuf_td = (uint*)alloc((size_t)NB * CAP * sizeof(uint));
    uint* ebuf_bu = (uint*)alloc((size_t)NB * CAP * sizeof(uint));
    ushort* csr_td = (ushort*)alloc((size_t)NB * CAP * sizeof(ushort));
    ushort* csr_bu = (ushort*)alloc((size_t)NB * CAP * sizeof(ushort));
    int* off_td = (int*)alloc((size_t)N_NODES * sizeof(int));
    int* off_bu = (int*)alloc((size_t)N_NODES * sizeof(int));
    ushort* deg_td = (ushort*)alloc((size_t)N_NODES * sizeof(ushort));
    ushort* deg_bu = (ushort*)alloc((size_t)N_NODES * sizeof(ushort));
    float* dinv_td = (float*)alloc((size_t)N_PAD * sizeof(float));
    float* dinv_bu = (float*)alloc((size_t)N_PAD * sizeof(float));
    ushort* Bt1 = (ushort*)alloc((size_t)256 * 256 * sizeof(ushort));
    ushort* Wt2 = (ushort*)alloc((size_t)128 * 256 * sizeof(ushort));
    ushort* linb = (ushort*)alloc((size_t)N_PAD * F_CAT * sizeof(ushort));
    ushort* h1s  = (ushort*)alloc((size_t)N_PAD * F_CAT * sizeof(ushort));
    float* partial = (float*)alloc((size_t)8 * B_AGG2 * PSLICE * sizeof(float)); // 32 MB

    hipMemsetAsync(gcur, 0, 1024, stream);

    // ---- weights prep ----
    prep_w_kernel<<<256, 256, 0, stream>>>(td_W1, bu_W1, td_W2, bu_W2, Bt1, Wt2);

    // ---- graph structure (bucketed counting sort; csr_build emits dinv) ----
    csr_scatter_kernel<<<N_EDGES / EPB, 256, 0, stream>>>(ei, gcur, ebuf_td, ebuf_bu);
    csr_build_kernel<<<dim3(NB, 2), 256, 0, stream>>>(ebuf_td, ebuf_bu, gcur,
        off_td, off_bu, deg_td, deg_bu, dinv_td, dinv_bu, csr_td, csr_bu);

    // ---- layer 1: GEMM (f32 A, in-register cvt; dinv ready) ----
    dim3 gg(N_PAD / 128, 2);
    gemm_mfma<<<gg, 256, 0, stream>>>(x, Bt1, linb, dinv_td, dinv_bu);
    agg1_kernel<<<AGG_BLOCKS, 256, 0, stream>>>(linb, h1s,
        csr_td, off_td, deg_td, dinv_td, csr_bu, off_bu, deg_bu, dinv_bu, td_b1, bu_b1);

    // ---- layer 2 + pool: source-major, LDS-resident graph accumulators ----
    agg2_pool_kernel<<<dim3(B_AGG2, 8), 256, 0, stream>>>(h1s, partial, batch,
        csr_td, off_td, deg_td, csr_bu, off_bu, deg_bu, dinv_td, dinv_bu);

    // ---- head: partial reduce + W2 matvec + cnt*b2 + MLP ----
    head_kernel<<<N_GRAPHS, 256, 0, stream>>>(partial, batch, Wt2,
        td_b2, bu_b2, pw1, pb1, pw2, pb2, out);
}

// Round 3
// 1382.174 us; speedup vs baseline: 1.0300x; 1.0300x over previous
//
#include <hip/hip_runtime.h>

#define N_NODES 50000
#define N_PAD   50048   // 391*128, GEMM epilogue needs no row guards
#define N_EDGES 800000
#define N_GRAPHS 512
#define F_IN 256
#define F_H 128
#define F_CAT 256

// bucketed CSR build
#define BSHIFT 9
#define NB 98           // ceil(50000/512) buckets
#define CAP 10240       // edge capacity per bucket (mean 8163, 23 sigma slack)
#define EPB 3125        // edges per scatter block (256 blocks)

#define AGG_BLOCKS 2048 // agg1 persistent grid: 8 blocks/CU on 256 CUs
#define B2 64           // agg2 blocks per pass; 4 passes -> 256 blocks (1/CU)
#define GSLICE (N_GRAPHS * 64)   // floats per pass accumulator (128 KB LDS)

typedef __attribute__((ext_vector_type(8))) short short8;
typedef __attribute__((ext_vector_type(4))) float f32x4;
typedef unsigned int uint;
typedef unsigned short ushort;

static __device__ __forceinline__ ushort f2bf(float f) {
    uint u = __float_as_uint(f);
    u += 0x7FFF + ((u >> 16) & 1);  // RNE
    return (ushort)(u >> 16);
}
static __device__ __forceinline__ float bflo(uint v) { return __uint_as_float(v << 16); }
static __device__ __forceinline__ float bfhi(uint v) { return __uint_as_float(v & 0xFFFF0000u); }
static __device__ __forceinline__ float bfu(ushort v) { return __uint_as_float((uint)v << 16); }

// async global->LDS, 16B per lane; lds base must be wave-uniform
#define GLL(g, l) __builtin_amdgcn_global_load_lds( \
    (const __attribute__((address_space(1))) unsigned int*)(g), \
    (__attribute__((address_space(3))) unsigned int*)(l), 16, 0, 0)

// ---------------------------------------------------------------------------
// S1: bucket-scatter edges. gcur is RELATIVE (zero-initialized by memset).
__global__ __launch_bounds__(256) void csr_scatter_kernel(
        const int* __restrict__ ei, int* __restrict__ gcur,
        uint* __restrict__ ebuf_td, uint* __restrict__ ebuf_bu) {
    __shared__ int lcnt[256];   // [dir*128 + bucket]
    __shared__ int lbase[256];
    int tid = threadIdx.x;
    lcnt[tid] = 0;
    __syncthreads();
    int e0 = blockIdx.x * EPB;
    for (int k = tid; k < EPB; k += 256) {
        int i = e0 + k;
        int s = ei[i], d = ei[N_EDGES + i];
        atomicAdd(&lcnt[d >> BSHIFT], 1);
        atomicAdd(&lcnt[128 + (s >> BSHIFT)], 1);
    }
    __syncthreads();
    if (tid < 2 * NB) {
        int dir = tid / NB, b = tid % NB;
        int c = lcnt[dir * 128 + b];
        lbase[dir * 128 + b] = c ? atomicAdd(&gcur[dir * NB + b], c) : 0;
    }
    __syncthreads();
    lcnt[tid] = 0;
    __syncthreads();
    for (int k = tid; k < EPB; k += 256) {
        int i = e0 + k;
        int s = ei[i], d = ei[N_EDGES + i];
        int bd = d >> BSHIFT, bs = s >> BSHIFT;
        int p = atomicAdd(&lcnt[bd], 1) + lbase[bd];
        ebuf_td[(size_t)bd * CAP + p] = (uint)s | ((uint)(d & 511) << 16);
        int q = atomicAdd(&lcnt[128 + bs], 1) + lbase[128 + bs];
        ebuf_bu[(size_t)bs * CAP + q] = (uint)d | ((uint)(s & 511) << 16);
    }
}

// ---------------------------------------------------------------------------
// S2: per-(bucket,dir) CSR build; also emits deg (u16) + dinv (free here,
// the node histogram already exists). Bucket-local scatter window.
__global__ __launch_bounds__(256) void csr_build_kernel(
        const uint* __restrict__ ebuf_td, const uint* __restrict__ ebuf_bu,
        const int* __restrict__ gcur,
        int* off_td, int* off_bu, ushort* deg_td, ushort* deg_bu,
        float* dinv_td, float* dinv_bu, ushort* csr_td, ushort* csr_bu) {
    int b = blockIdx.x, dir = blockIdx.y;
    const uint* ebuf = dir ? ebuf_bu : ebuf_td;
    int* off     = dir ? off_bu : off_td;
    ushort* deg  = dir ? deg_bu : deg_td;
    float* dinv  = dir ? dinv_bu : dinv_td;
    ushort* csr  = dir ? csr_bu : csr_td;
    __shared__ int cntL[512], offL[512], sm[256];
    int tid = threadIdx.x;
    cntL[tid] = 0; cntL[tid + 256] = 0;
    __syncthreads();
    int rbeg = b * CAP;
    int rend = rbeg + gcur[dir * NB + b];
    for (int k = rbeg + tid; k < rend; k += 256)
        atomicAdd(&cntL[ebuf[k] >> 16], 1);
    __syncthreads();
    int a0 = cntL[tid * 2], a1 = cntL[tid * 2 + 1];
    int ps = a0 + a1;
    sm[tid] = ps;
    __syncthreads();
    for (int o = 1; o < 256; o <<= 1) {
        int u = (tid >= o) ? sm[tid - o] : 0;
        __syncthreads();
        sm[tid] += u;
        __syncthreads();
    }
    int excl = sm[tid] - ps;
    offL[tid * 2] = excl;
    offL[tid * 2 + 1] = excl + a0;
    __syncthreads();
    int nbase = b << BSHIFT;
#pragma unroll
    for (int j = 0; j < 2; j++) {
        int nloc = tid + j * 256;
        int n = nbase + nloc;
        if (n < N_NODES) {
            off[n] = rbeg + offL[nloc];
            int c = cntL[nloc];
            deg[n] = (ushort)c;
            dinv[n] = rsqrtf((float)c + 1.0f);
        }
    }
    // pad rows (only needed once; bucket NB-1, dir both cover [50000, N_PAD))
    if (b == NB - 1) {
        int n = N_NODES + tid;
        if (n < N_PAD) dinv[n] = 1.0f;
    }
    cntL[tid] = offL[tid];
    cntL[tid + 256] = offL[tid + 256];
    __syncthreads();
    for (int k = rbeg + tid; k < rend; k += 256) {
        uint e = ebuf[k];
        int slot = atomicAdd(&cntL[e >> 16], 1);
        csr[rbeg + slot] = (ushort)(e & 0xFFFF);
    }
}

// ---------------------------------------------------------------------------
// Per-edge (graph,weight) tables aligned with CSR slots, for push-mode agg2.
// dir=0: csr_td slots (targets are sources s)      -> gw_bu: {batch[s]<<8, dinv_bu[s]}
// dir=1: csr_bu slots (targets are destinations d) -> gw_td: {batch[d]<<8, dinv_td[d]}
__global__ __launch_bounds__(256) void gw_prep_kernel(
        const ushort* __restrict__ csr_td, const ushort* __restrict__ csr_bu,
        const int* __restrict__ gcur, const int* __restrict__ batch,
        const float* __restrict__ dinv_td, const float* __restrict__ dinv_bu,
        uint2* __restrict__ gw_td, uint2* __restrict__ gw_bu) {
    int b = blockIdx.x, dir = blockIdx.y;
    const ushort* csr = dir ? csr_bu : csr_td;
    const float* dv   = dir ? dinv_td : dinv_bu;
    uint2* gw         = dir ? gw_td : gw_bu;
    int rbeg = b * CAP;
    int rend = rbeg + gcur[dir * NB + b];
    for (int k = rbeg + threadIdx.x; k < rend; k += 256) {
        int t = csr[k];
        gw[k] = make_uint2((uint)batch[t] << 8, __float_as_uint(dv[t]));
    }
}

// ---------------------------------------------------------------------------
// Bt1[n][k]; Wt2[k][c] with c in concat([bu, td]) order.
__global__ void prep_w_kernel(const float* __restrict__ td_W1, const float* __restrict__ bu_W1,
                              const float* __restrict__ td_W2, const float* __restrict__ bu_W2,
                              ushort* __restrict__ Bt1, ushort* __restrict__ Wt2) {
    int n = blockIdx.x;   // 0..255
    int k = threadIdx.x;  // 0..255
    float w1 = (n < F_H) ? td_W1[(size_t)k * F_H + n] : bu_W1[(size_t)k * F_H + (n - F_H)];
    Bt1[(size_t)n * 256 + k] = f2bf(w1);
    if (k < 128) {
        float w2 = (n < F_H) ? bu_W2[(size_t)k * F_H + n]
                             : td_W2[(size_t)k * F_H + (n - F_H)];
        Wt2[(size_t)k * 256 + n] = f2bf(w2);
    }
}

// ---------------------------------------------------------------------------
// MFMA GEMM (layer 1): A = x f32 (in-register bf16 convert), B via GLL,
// C = linb bf16 row-scaled by branch dinv. 128x128 tile, BK=32, 4 waves.
__global__ __launch_bounds__(256) void gemm_mfma(
        const float* __restrict__ x, const ushort* __restrict__ Bt,
        ushort* __restrict__ C,
        const float* __restrict__ dinv_td, const float* __restrict__ dinv_bu) {
    __shared__ __align__(16) ushort As[128 * 32];
    __shared__ __align__(16) ushort Bs[128 * 32];
    int tid = threadIdx.x;
    int wave = tid >> 6, lane = tid & 63, quad = lane >> 4, l16 = lane & 15;
    size_t bm = (size_t)blockIdx.x * 128;
    size_t bn = (size_t)blockIdx.y * 128;
    const float* dsel = blockIdx.y ? dinv_bu : dinv_td;

    f32x4 acc[2][8];
    const f32x4 z4 = {0.f, 0.f, 0.f, 0.f};
#pragma unroll
    for (int i = 0; i < 2; i++)
#pragma unroll
        for (int j = 0; j < 8; j++) acc[i][j] = z4;

    int ar = tid >> 3;          // 0..31
    int akq = (tid & 7) * 4;    // 0..28
    int cb0 = wave * 64;
    int cb1 = 256 + wave * 64;
    int c0 = cb0 + lane, c1 = cb1 + lane;
    int r0 = c0 >> 2, s0 = (c0 & 3) * 8;
    int r1 = c1 >> 2, s1 = (c1 & 3) * 8;
    const ushort* b0p = Bt + (bn + r0) * 256 + s0;
    const ushort* b1p = Bt + (bn + r1) * 256 + s1;
    ushort* lB0 = Bs + cb0 * 8;
    ushort* lB1 = Bs + cb1 * 8;

    for (int kb = 0; kb < 8; kb++) {
        int k0 = kb * 32;
        float4 av[4];
#pragma unroll
        for (int j = 0; j < 4; j++) {
            size_t grow = bm + ar + j * 32;
            if (grow < N_NODES)
                av[j] = *(const float4*)(x + grow * F_IN + k0 + akq);
            else
                av[j] = make_float4(0.f, 0.f, 0.f, 0.f);
        }
        __syncthreads();  // previous iter's fragment reads done
        GLL(b0p + k0, lB0);
        GLL(b1p + k0, lB1);
#pragma unroll
        for (int j = 0; j < 4; j++) {
            ushort4 u;
            u.x = f2bf(av[j].x); u.y = f2bf(av[j].y);
            u.z = f2bf(av[j].z); u.w = f2bf(av[j].w);
            *(ushort4*)(As + (ar + j * 32) * 32 + akq) = u;
        }
        __syncthreads();  // drains vmcnt + lgkm, tiles ready
        short8 af0 = *(const short8*)(As + (wave * 32 + l16) * 32 + quad * 8);
        short8 af1 = *(const short8*)(As + (wave * 32 + 16 + l16) * 32 + quad * 8);
#pragma unroll
        for (int ct = 0; ct < 8; ct++) {
            short8 bfr = *(const short8*)(Bs + (ct * 16 + l16) * 32 + quad * 8);
            acc[0][ct] = __builtin_amdgcn_mfma_f32_16x16x32_bf16(af0, bfr, acc[0][ct], 0, 0, 0);
            acc[1][ct] = __builtin_amdgcn_mfma_f32_16x16x32_bf16(af1, bfr, acc[1][ct], 0, 0, 0);
        }
    }
#pragma unroll
    for (int rt = 0; rt < 2; rt++) {
#pragma unroll
        for (int r = 0; r < 4; r++) {
            size_t row = bm + wave * 32 + rt * 16 + quad * 4 + r;
            float dv = dsel[row];
#pragma unroll
            for (int ct = 0; ct < 8; ct++) {
                C[row * 256 + bn + ct * 16 + l16] = f2bf(acc[rt][ct][r] * dv);
            }
        }
    }
}

// ---------------------------------------------------------------------------
// Wave-gather: 16 lanes per edge row (uint4 = 8 bf16 cols per lane),
// 4 edge slots (q = lane>>4) concurrently; unroll-4 -> 16 edges in flight.
static __device__ __forceinline__ void acc8(float a[8], uint4 v) {
    a[0] += bflo(v.x); a[1] += bfhi(v.x);
    a[2] += bflo(v.y); a[3] += bfhi(v.y);
    a[4] += bflo(v.z); a[5] += bfhi(v.z);
    a[6] += bflo(v.w); a[7] += bfhi(v.w);
}

static __device__ __forceinline__ void gather_node4(
        const ushort* __restrict__ base, const ushort* __restrict__ csr,
        int kb, int ke, int q, float a[8]) {
    int k = kb;
    for (; k + 16 <= ke; k += 16) {
        int i0 = csr[k + q],      i1 = csr[k + 4 + q];
        int i2 = csr[k + 8 + q],  i3 = csr[k + 12 + q];
        uint4 v0 = *(const uint4*)(base + (size_t)i0 * F_CAT);
        uint4 v1 = *(const uint4*)(base + (size_t)i1 * F_CAT);
        uint4 v2 = *(const uint4*)(base + (size_t)i2 * F_CAT);
        uint4 v3 = *(const uint4*)(base + (size_t)i3 * F_CAT);
        acc8(a, v0); acc8(a, v1); acc8(a, v2); acc8(a, v3);
    }
    for (; k + 4 <= ke; k += 4) {
        uint4 v = *(const uint4*)(base + (size_t)csr[k + q] * F_CAT);
        acc8(a, v);
    }
    if (k + q < ke) {
        uint4 v = *(const uint4*)(base + (size_t)csr[k + q] * F_CAT);
        acc8(a, v);
    }
}

// ---------------------------------------------------------------------------
// Layer-1 aggregation: persistent grid, contiguous per-wave node chunks.
// h1s[n] = relu(dn*(self+neigh) + b1) * dn   (dinv pre-folded for layer 2)
__global__ __launch_bounds__(256, 8) void agg1_kernel(
        const ushort* __restrict__ linS, ushort* __restrict__ h1s,
        const ushort* __restrict__ csr_td, const int* __restrict__ off_td,
        const ushort* __restrict__ deg_td, const float* __restrict__ dinv_td,
        const ushort* __restrict__ csr_bu, const int* __restrict__ off_bu,
        const ushort* __restrict__ deg_bu, const float* __restrict__ dinv_bu,
        const float* __restrict__ b_td, const float* __restrict__ b_bu) {
    int lane = threadIdx.x & 63;
    int wid = blockIdx.x * 4 + (threadIdx.x >> 6);
    int br = wid & 1;           // branch fixed per wave
    int wq = wid >> 1;          // wave index within branch, 0..4095
    const int WPB = AGG_BLOCKS * 2;   // waves per branch
    int beg = (int)(((long long)wq * N_NODES) / WPB);
    int end = (int)(((long long)(wq + 1) * N_NODES) / WPB);
    const ushort* csr = br ? csr_bu : csr_td;
    const int* off    = br ? off_bu : off_td;
    const ushort* deg = br ? deg_bu : deg_td;
    const float* dinv = br ? dinv_bu : dinv_td;
    const float* bias = br ? b_bu : b_td;
    int q = lane >> 4, c = lane & 15;
    int col = br * F_H + c * 8;
    const ushort* base = linS + col;
    float bs[8];
#pragma unroll
    for (int j = 0; j < 8; j++) bs[j] = bias[c * 8 + j];

    for (int n = beg; n < end; ++n) {
        float a[8] = {0.f, 0.f, 0.f, 0.f, 0.f, 0.f, 0.f, 0.f};
        int kb = off[n];
        gather_node4(base, csr, kb, kb + deg[n], q, a);
#pragma unroll
        for (int u = 0; u < 8; u++) {
            a[u] += __shfl_xor(a[u], 16);
            a[u] += __shfl_xor(a[u], 32);
        }
        uint4 vs = *(const uint4*)(base + (size_t)n * F_CAT);  // self
        acc8(a, vs);
        float dn = dinv[n];
        if (q == 0) {
            float o[8];
#pragma unroll
            for (int u = 0; u < 8; u++) o[u] = fmaxf(a[u] * dn + bs[u], 0.f) * dn;
            uint4 pk;
            pk.x = (uint)f2bf(o[0]) | ((uint)f2bf(o[1]) << 16);
            pk.y = (uint)f2bf(o[2]) | ((uint)f2bf(o[3]) << 16);
            pk.z = (uint)f2bf(o[4]) | ((uint)f2bf(o[5]) << 16);
            pk.w = (uint)f2bf(o[6]) | ((uint)f2bf(o[7]) << 16);
            *(uint4*)(h1s + (size_t)n * F_CAT + col) = pk;
        }
    }
}

// ---------------------------------------------------------------------------
// Layer-2 + pool, PUSH mode: pooled = C^T * h1s where C[s,g] holds edge
// weights. Sequential h1s stream (no 256B random gathers); per-edge (g,w)
// pre-packed in gw[]; native ds_add_f32 into a 512x64 f32 LDS accumulator.
// Passes: 0,1 = TD cols 0..127 (walk out-edges via off_bu, gw_td);
//         2,3 = BU cols 128..255 (walk in-edges via off_td, gw_bu).
// One source node per wave; 64 lanes = 64 cols; edge loop is wave-uniform.
__global__ __launch_bounds__(512, 1) void agg2_push_kernel(
        const ushort* __restrict__ h1s, float* __restrict__ partial,
        const int* __restrict__ batch,
        const int* __restrict__ off_td, const ushort* __restrict__ deg_td,
        const int* __restrict__ off_bu, const ushort* __restrict__ deg_bu,
        const float* __restrict__ dinv_td, const float* __restrict__ dinv_bu,
        const uint2* __restrict__ gw_td, const uint2* __restrict__ gw_bu) {
    __shared__ __align__(16) float acc[GSLICE];   // 512 graphs x 64 cols = 128 KB
    int tid = threadIdx.x;
    int pass = blockIdx.y;          // 0..3
    int b = blockIdx.x;             // 0..B2-1
    for (int i = tid; i < GSLICE; i += 512) acc[i] = 0.f;
    __syncthreads();

    int br = pass >> 1;             // 0 = TD, 1 = BU
    const int*    off = br ? off_td : off_bu;
    const ushort* deg = br ? deg_td : deg_bu;
    const uint2*  gw  = br ? gw_bu  : gw_td;
    const float*  dvs = br ? dinv_bu : dinv_td;

    int c = tid & 63;               // lane = col within slice
    int w = tid >> 6;               // wave 0..7
    int wq = b * 8 + w;             // 0..511
    int beg = (int)(((long long)wq * N_NODES) / (B2 * 8));
    int end = (int)(((long long)(wq + 1) * N_NODES) / (B2 * 8));
    int hb = pass * 64 + c;         // h1s column
    uint myoff = (uint)(size_t)((__attribute__((address_space(3))) float*)acc)
               + (uint)(c * 4);

    for (int n = beg; n < end; ++n) {
        int o = off[n];
        int dg = deg[n];
        float hv = bfu(h1s[(size_t)n * F_CAT + hb]);
        // self term: dinv_x[n] * h1s[n] -> batch[n]
        uint saddr = myoff + ((uint)batch[n] << 8);
        float sv = dvs[n] * hv;
        asm volatile("ds_add_f32 %0, %1" :: "v"(saddr), "v"(sv));
        for (int kb = 0; kb < dg; kb += 64) {
            int m = dg - kb; if (m > 64) m = 64;
            uint2 e = gw[o + kb + ((c < m) ? c : 0)];   // lane k holds edge k
            for (int k = 0; k < m; ++k) {
                uint go = (uint)__builtin_amdgcn_readlane((int)e.x, k);
                uint wb = (uint)__builtin_amdgcn_readlane((int)e.y, k);
                float v = __uint_as_float(wb) * hv;
                uint addr = myoff + go;
                asm volatile("ds_add_f32 %0, %1" :: "v"(addr), "v"(v));
            }
        }
    }
    asm volatile("s_waitcnt lgkmcnt(0)");   // drain asm-issued ds_adds
    __syncthreads();
    float* pp = partial + ((size_t)(pass * B2 + b)) * GSLICE;
    const f32x4* a4 = (const f32x4*)acc;
    f32x4* p4 = (f32x4*)pp;
    for (int i = tid; i < GSLICE / 4; i += 512) p4[i] = a4[i];
}

// ---------------------------------------------------------------------------
// Head: row = 64-way reduce of partials (col = pass*64+c, same layout as
// pooled_pre), then z = row@W2 + cnt*b2 in concat([bu,td]) order, then
// MLP relu(z@pw1+pb1)@pw2+pb2. One block per graph.
__global__ __launch_bounds__(256) void head_kernel(
        const float* __restrict__ partial, const int* __restrict__ batch,
        const ushort* __restrict__ Wt2,
        const float* __restrict__ td_b2, const float* __restrict__ bu_b2,
        const float* __restrict__ pw1, const float* __restrict__ pb1,
        const float* __restrict__ pw2, const float* __restrict__ pb2,
        float* __restrict__ out) {
    int g = blockIdx.x;
    int tid = threadIdx.x;
    __shared__ float row[256], z[256], hid[256];
    int pass = tid >> 6, cc = tid & 63;
    const float* pp = partial + (size_t)pass * B2 * GSLICE + (size_t)g * 64 + cc;
    float s = 0.f;
    for (int b2 = 0; b2 < B2; ++b2) s += pp[(size_t)b2 * GSLICE];
    row[tid] = s;
    int lo = 0, hi = N_NODES;
    while (lo < hi) { int m = (lo + hi) >> 1; if (batch[m] < g) lo = m + 1; else hi = m; }
    int start = lo;
    lo = start; hi = N_NODES;
    while (lo < hi) { int m = (lo + hi) >> 1; if (batch[m] < g + 1) lo = m + 1; else hi = m; }
    float cnt = (float)(lo - start);
    __syncthreads();
    const float* rsel = (tid < 128) ? (row + F_H) : row;
    float b2v = (tid < 128) ? bu_b2[tid] : td_b2[tid - F_H];
    float acc = cnt * b2v;
    for (int k = 0; k < F_H; k++) acc += rsel[k] * bfu(Wt2[(size_t)k * 256 + tid]);
    z[tid] = acc;
    __syncthreads();
    float hh = pb1[tid];
    for (int k = 0; k < 256; k++) hh += z[k] * pw1[(size_t)k * 256 + tid];
    hid[tid] = fmaxf(hh, 0.f);
    __syncthreads();
    if (tid < 128) {
        float o = pb2[tid];
        for (int k = 0; k < 256; k++) o += hid[k] * pw2[(size_t)k * 128 + tid];
        out[(size_t)g * 128 + tid] = o;
    }
}

// ---------------------------------------------------------------------------
extern "C" void kernel_launch(void* const* d_in, const int* in_sizes, int n_in,
                              void* d_out, int out_size, void* d_ws, size_t ws_size,
                              hipStream_t stream) {
    const float* x     = (const float*)d_in[0];
    const int*   ei    = (const int*)d_in[1];
    const int*   batch = (const int*)d_in[2];
    const float* td_W1 = (const float*)d_in[4];
    const float* td_b1 = (const float*)d_in[5];
    const float* td_W2 = (const float*)d_in[6];
    const float* td_b2 = (const float*)d_in[7];
    const float* bu_W1 = (const float*)d_in[8];
    const float* bu_b1 = (const float*)d_in[9];
    const float* bu_W2 = (const float*)d_in[10];
    const float* bu_b2 = (const float*)d_in[11];
    const float* pw1   = (const float*)d_in[12];
    const float* pb1   = (const float*)d_in[13];
    const float* pw2   = (const float*)d_in[14];
    const float* pb2   = (const float*)d_in[15];
    float* out = (float*)d_out;

    // ---- workspace carve ----
    // Aliasing plan: partial (32 MB, live agg2->head) reuses
    // [ebuf_td | ebuf_bu | linb] (8 MB + 25.6 MB; ebuf dead after csr_build,
    // linb dead after agg1).
    char* p = (char*)d_ws;
    auto alloc = [&](size_t bytes) { void* r = (void*)p; p += (bytes + 255) & ~(size_t)255; return r; };
    int* gcur = (int*)alloc(1024);           // memset region (scatter cursors)
    uint* ebuf_td = (uint*)alloc((size_t)NB * CAP * sizeof(uint));
    uint* ebuf_bu = (uint*)alloc((size_t)NB * CAP * sizeof(uint));
    ushort* linb = (ushort*)alloc((size_t)N_PAD * F_CAT * sizeof(ushort));
    float* partial = (float*)ebuf_td;        // 4*B2*GSLICE*4 = 32 MB <= 33.65 MB
    ushort* csr_td = (ushort*)alloc((size_t)NB * CAP * sizeof(ushort));
    ushort* csr_bu = (ushort*)alloc((size_t)NB * CAP * sizeof(ushort));
    int* off_td = (int*)alloc((size_t)N_NODES * sizeof(int));
    int* off_bu = (int*)alloc((size_t)N_NODES * sizeof(int));
    ushort* deg_td = (ushort*)alloc((size_t)N_NODES * sizeof(ushort));
    ushort* deg_bu = (ushort*)alloc((size_t)N_NODES * sizeof(ushort));
    float* dinv_td = (float*)alloc((size_t)N_PAD * sizeof(float));
    float* dinv_bu = (float*)alloc((size_t)N_PAD * sizeof(float));
    ushort* Bt1 = (ushort*)alloc((size_t)256 * 256 * sizeof(ushort));
    ushort* Wt2 = (ushort*)alloc((size_t)128 * 256 * sizeof(ushort));
    ushort* h1s  = (ushort*)alloc((size_t)N_PAD * F_CAT * sizeof(ushort));
    uint2* gw_td = (uint2*)alloc((size_t)NB * CAP * sizeof(uint2));
    uint2* gw_bu = (uint2*)alloc((size_t)NB * CAP * sizeof(uint2));

    hipMemsetAsync(gcur, 0, 1024, stream);

    // ---- weights prep ----
    prep_w_kernel<<<256, 256, 0, stream>>>(td_W1, bu_W1, td_W2, bu_W2, Bt1, Wt2);

    // ---- graph structure (bucketed counting sort; csr_build emits dinv) ----
    csr_scatter_kernel<<<N_EDGES / EPB, 256, 0, stream>>>(ei, gcur, ebuf_td, ebuf_bu);
    csr_build_kernel<<<dim3(NB, 2), 256, 0, stream>>>(ebuf_td, ebuf_bu, gcur,
        off_td, off_bu, deg_td, deg_bu, dinv_td, dinv_bu, csr_td, csr_bu);
    gw_prep_kernel<<<dim3(NB, 2), 256, 0, stream>>>(csr_td, csr_bu, gcur, batch,
        dinv_td, dinv_bu, gw_td, gw_bu);

    // ---- layer 1: GEMM (f32 A, in-register cvt; dinv ready) ----
    dim3 gg(N_PAD / 128, 2);
    gemm_mfma<<<gg, 256, 0, stream>>>(x, Bt1, linb, dinv_td, dinv_bu);
    agg1_kernel<<<AGG_BLOCKS, 256, 0, stream>>>(linb, h1s,
        csr_td, off_td, deg_td, dinv_td, csr_bu, off_bu, deg_bu, dinv_bu, td_b1, bu_b1);

    // ---- layer 2 + pool: push mode with native LDS f32 atomics ----
    agg2_push_kernel<<<dim3(B2, 4), 512, 0, stream>>>(h1s, partial, batch,
        off_td, deg_td, off_bu, deg_bu, dinv_td, dinv_bu, gw_td, gw_bu);

    // ---- head: partial reduce + W2 matvec + cnt*b2 + MLP ----
    head_kernel<<<N_GRAPHS, 256, 0, stream>>>(partial, batch, Wt2,
        td_b2, bu_b2, pw1, pb1, pw2, pb2, out);
}

// Round 4
// 405.585 us; speedup vs baseline: 3.5099x; 3.4078x over previous
//
#include <hip/hip_runtime.h>

#define N_NODES 50000
#define N_PAD   50048   // 391*128, GEMM epilogue needs no row guards
#define N_EDGES 800000
#define N_GRAPHS 512
#define F_IN 256
#define F_H 128
#define F_CAT 256

// bucketed CSR build
#define BSHIFT 9
#define NB 98           // ceil(50000/512) buckets
#define CAP 10240       // edge capacity per bucket (mean 8163, 23 sigma slack)
#define EPB 3125        // edges per scatter block (256 blocks)

// sliced aggregation: 16 (branch,slice) pairs; pair pool = N_PAD x 16 ushorts
#define NPAIR 16
#define SLICE_C 16
#define POOL_STRIDE ((size_t)N_PAD * SLICE_C)
#define AGG_CHUNK 128             // blocks per pair; 16*128 = 2048 blocks
#define N_GROUPS (N_NODES / 4)    // 12500 groups of 4 nodes

typedef __attribute__((ext_vector_type(8))) short short8;
typedef __attribute__((ext_vector_type(4))) float f32x4;
typedef unsigned int uint;
typedef unsigned short ushort;

static __device__ __forceinline__ ushort f2bf(float f) {
    uint u = __float_as_uint(f);
    u += 0x7FFF + ((u >> 16) & 1);  // RNE
    return (ushort)(u >> 16);
}
static __device__ __forceinline__ float bflo(uint v) { return __uint_as_float(v << 16); }
static __device__ __forceinline__ float bfhi(uint v) { return __uint_as_float(v & 0xFFFF0000u); }
static __device__ __forceinline__ float bfu(ushort v) { return __uint_as_float((uint)v << 16); }

// async global->LDS, 16B per lane; lds base must be wave-uniform
#define GLL(g, l) __builtin_amdgcn_global_load_lds( \
    (const __attribute__((address_space(1))) unsigned int*)(g), \
    (__attribute__((address_space(3))) unsigned int*)(l), 16, 0, 0)

// ---------------------------------------------------------------------------
// S1: bucket-scatter edges. gcur is RELATIVE (zero-initialized by memset).
__global__ __launch_bounds__(256) void csr_scatter_kernel(
        const int* __restrict__ ei, int* __restrict__ gcur,
        uint* __restrict__ ebuf_td, uint* __restrict__ ebuf_bu) {
    __shared__ int lcnt[256];   // [dir*128 + bucket]
    __shared__ int lbase[256];
    int tid = threadIdx.x;
    lcnt[tid] = 0;
    __syncthreads();
    int e0 = blockIdx.x * EPB;
    for (int k = tid; k < EPB; k += 256) {
        int i = e0 + k;
        int s = ei[i], d = ei[N_EDGES + i];
        atomicAdd(&lcnt[d >> BSHIFT], 1);
        atomicAdd(&lcnt[128 + (s >> BSHIFT)], 1);
    }
    __syncthreads();
    if (tid < 2 * NB) {
        int dir = tid / NB, b = tid % NB;
        int c = lcnt[dir * 128 + b];
        lbase[dir * 128 + b] = c ? atomicAdd(&gcur[dir * NB + b], c) : 0;
    }
    __syncthreads();
    lcnt[tid] = 0;
    __syncthreads();
    for (int k = tid; k < EPB; k += 256) {
        int i = e0 + k;
        int s = ei[i], d = ei[N_EDGES + i];
        int bd = d >> BSHIFT, bs = s >> BSHIFT;
        int p = atomicAdd(&lcnt[bd], 1) + lbase[bd];
        ebuf_td[(size_t)bd * CAP + p] = (uint)s | ((uint)(d & 511) << 16);
        int q = atomicAdd(&lcnt[128 + bs], 1) + lbase[128 + bs];
        ebuf_bu[(size_t)bs * CAP + q] = (uint)d | ((uint)(s & 511) << 16);
    }
}

// ---------------------------------------------------------------------------
// S2: per-(bucket,dir) CSR build; also emits deg (u16) + dinv.
__global__ __launch_bounds__(256) void csr_build_kernel(
        const uint* __restrict__ ebuf_td, const uint* __restrict__ ebuf_bu,
        const int* __restrict__ gcur,
        int* off_td, int* off_bu, ushort* deg_td, ushort* deg_bu,
        float* dinv_td, float* dinv_bu, ushort* csr_td, ushort* csr_bu) {
    int b = blockIdx.x, dir = blockIdx.y;
    const uint* ebuf = dir ? ebuf_bu : ebuf_td;
    int* off     = dir ? off_bu : off_td;
    ushort* deg  = dir ? deg_bu : deg_td;
    float* dinv  = dir ? dinv_bu : dinv_td;
    ushort* csr  = dir ? csr_bu : csr_td;
    __shared__ int cntL[512], offL[512], sm[256];
    int tid = threadIdx.x;
    cntL[tid] = 0; cntL[tid + 256] = 0;
    __syncthreads();
    int rbeg = b * CAP;
    int rend = rbeg + gcur[dir * NB + b];
    for (int k = rbeg + tid; k < rend; k += 256)
        atomicAdd(&cntL[ebuf[k] >> 16], 1);
    __syncthreads();
    int a0 = cntL[tid * 2], a1 = cntL[tid * 2 + 1];
    int ps = a0 + a1;
    sm[tid] = ps;
    __syncthreads();
    for (int o = 1; o < 256; o <<= 1) {
        int u = (tid >= o) ? sm[tid - o] : 0;
        __syncthreads();
        sm[tid] += u;
        __syncthreads();
    }
    int excl = sm[tid] - ps;
    offL[tid * 2] = excl;
    offL[tid * 2 + 1] = excl + a0;
    __syncthreads();
    int nbase = b << BSHIFT;
#pragma unroll
    for (int j = 0; j < 2; j++) {
        int nloc = tid + j * 256;
        int n = nbase + nloc;
        if (n < N_NODES) {
            off[n] = rbeg + offL[nloc];
            int c = cntL[nloc];
            deg[n] = (ushort)c;
            dinv[n] = rsqrtf((float)c + 1.0f);
        }
    }
    // pad rows
    if (b == NB - 1) {
        int n = N_NODES + tid;
        if (n < N_PAD) dinv[n] = 1.0f;
    }
    cntL[tid] = offL[tid];
    cntL[tid + 256] = offL[tid + 256];
    __syncthreads();
    for (int k = rbeg + tid; k < rend; k += 256) {
        uint e = ebuf[k];
        int slot = atomicAdd(&cntL[e >> 16], 1);
        csr[rbeg + slot] = (ushort)(e & 0xFFFF);
    }
}

// ---------------------------------------------------------------------------
// Bt1[n][k]; Wt2[k][c] with c in concat([bu, td]) order.
__global__ void prep_w_kernel(const float* __restrict__ td_W1, const float* __restrict__ bu_W1,
                              const float* __restrict__ td_W2, const float* __restrict__ bu_W2,
                              ushort* __restrict__ Bt1, ushort* __restrict__ Wt2) {
    int n = blockIdx.x;   // 0..255
    int k = threadIdx.x;  // 0..255
    float w1 = (n < F_H) ? td_W1[(size_t)k * F_H + n] : bu_W1[(size_t)k * F_H + (n - F_H)];
    Bt1[(size_t)n * 256 + k] = f2bf(w1);
    if (k < 128) {
        float w2 = (n < F_H) ? bu_W2[(size_t)k * F_H + n]
                             : td_W2[(size_t)k * F_H + (n - F_H)];
        Wt2[(size_t)k * 256 + n] = f2bf(w2);
    }
}

// ---------------------------------------------------------------------------
// MFMA GEMM (layer 1): A = x f32 (in-register bf16 convert), B via GLL,
// C = linb bf16 row-scaled by branch dinv, written SLICE-MAJOR:
// pool (br*8+ct), row n, col l16  ->  linb[pair*POOL_STRIDE + n*16 + l16].
__global__ __launch_bounds__(256) void gemm_mfma(
        const float* __restrict__ x, const ushort* __restrict__ Bt,
        ushort* __restrict__ C,
        const float* __restrict__ dinv_td, const float* __restrict__ dinv_bu) {
    __shared__ __align__(16) ushort As[128 * 32];
    __shared__ __align__(16) ushort Bs[128 * 32];
    int tid = threadIdx.x;
    int wave = tid >> 6, lane = tid & 63, quad = lane >> 4, l16 = lane & 15;
    size_t bm = (size_t)blockIdx.x * 128;
    size_t bn = (size_t)blockIdx.y * 128;
    int br = blockIdx.y;
    const float* dsel = br ? dinv_bu : dinv_td;

    f32x4 acc[2][8];
    const f32x4 z4 = {0.f, 0.f, 0.f, 0.f};
#pragma unroll
    for (int i = 0; i < 2; i++)
#pragma unroll
        for (int j = 0; j < 8; j++) acc[i][j] = z4;

    int ar = tid >> 3;          // 0..31
    int akq = (tid & 7) * 4;    // 0..28
    int cb0 = wave * 64;
    int cb1 = 256 + wave * 64;
    int c0 = cb0 + lane, c1 = cb1 + lane;
    int r0 = c0 >> 2, s0 = (c0 & 3) * 8;
    int r1 = c1 >> 2, s1 = (c1 & 3) * 8;
    const ushort* b0p = Bt + (bn + r0) * 256 + s0;
    const ushort* b1p = Bt + (bn + r1) * 256 + s1;
    ushort* lB0 = Bs + cb0 * 8;
    ushort* lB1 = Bs + cb1 * 8;

    for (int kb = 0; kb < 8; kb++) {
        int k0 = kb * 32;
        float4 av[4];
#pragma unroll
        for (int j = 0; j < 4; j++) {
            size_t grow = bm + ar + j * 32;
            if (grow < N_NODES)
                av[j] = *(const float4*)(x + grow * F_IN + k0 + akq);
            else
                av[j] = make_float4(0.f, 0.f, 0.f, 0.f);
        }
        __syncthreads();  // previous iter's fragment reads done
        GLL(b0p + k0, lB0);
        GLL(b1p + k0, lB1);
#pragma unroll
        for (int j = 0; j < 4; j++) {
            ushort4 u;
            u.x = f2bf(av[j].x); u.y = f2bf(av[j].y);
            u.z = f2bf(av[j].z); u.w = f2bf(av[j].w);
            *(ushort4*)(As + (ar + j * 32) * 32 + akq) = u;
        }
        __syncthreads();  // drains vmcnt + lgkm, tiles ready
        short8 af0 = *(const short8*)(As + (wave * 32 + l16) * 32 + quad * 8);
        short8 af1 = *(const short8*)(As + (wave * 32 + 16 + l16) * 32 + quad * 8);
#pragma unroll
        for (int ct = 0; ct < 8; ct++) {
            short8 bfr = *(const short8*)(Bs + (ct * 16 + l16) * 32 + quad * 8);
            acc[0][ct] = __builtin_amdgcn_mfma_f32_16x16x32_bf16(af0, bfr, acc[0][ct], 0, 0, 0);
            acc[1][ct] = __builtin_amdgcn_mfma_f32_16x16x32_bf16(af1, bfr, acc[1][ct], 0, 0, 0);
        }
    }
#pragma unroll
    for (int rt = 0; rt < 2; rt++) {
#pragma unroll
        for (int r = 0; r < 4; r++) {
            size_t row = bm + wave * 32 + rt * 16 + quad * 4 + r;
            float dv = dsel[row];
#pragma unroll
            for (int ct = 0; ct < 8; ct++) {
                C[(size_t)(br * 8 + ct) * POOL_STRIDE + row * 16 + l16] =
                    f2bf(acc[rt][ct][r] * dv);
            }
        }
    }
}

// ---------------------------------------------------------------------------
// Sliced gather helpers. Wave layout: lane = nj*16 + es*2 + half
//   nj   = node within 4-node group (lane bits 4..5)
//   es   = edge slot 0..7           (lane bits 1..3)
//   half = 16B half of 32B row      (lane bit 0)
static __device__ __forceinline__ void acc8(float a[8], uint4 v) {
    a[0] += bflo(v.x); a[1] += bfhi(v.x);
    a[2] += bflo(v.y); a[3] += bfhi(v.y);
    a[4] += bflo(v.z); a[5] += bfhi(v.z);
    a[6] += bflo(v.w); a[7] += bfhi(v.w);
}

// ---------------------------------------------------------------------------
// Layer-1 aggregation, sliced. Block b -> pair = b&15 (XCD-pinned under
// round-robin dispatch), chunk = b>>4. Pool = linb slice (1.6 MB, L2-fit).
// h1s2[n] = relu(dn*(self+neigh) + b1) * dn, slice-major output.
__global__ __launch_bounds__(256, 8) void agg1s_kernel(
        const ushort* __restrict__ linS2, ushort* __restrict__ h1s2,
        const ushort* __restrict__ csr_td, const int* __restrict__ off_td,
        const ushort* __restrict__ deg_td, const float* __restrict__ dinv_td,
        const ushort* __restrict__ csr_bu, const int* __restrict__ off_bu,
        const ushort* __restrict__ deg_bu, const float* __restrict__ dinv_bu,
        const float* __restrict__ b_td, const float* __restrict__ b_bu) {
    int b = blockIdx.x;
    int pair = b & 15;
    int chunk = b >> 4;
    int br = pair >> 3, s = pair & 7;
    const ushort* csr = br ? csr_bu : csr_td;
    const int* off    = br ? off_bu : off_td;
    const ushort* deg = br ? deg_bu : deg_td;
    const float* dinv = br ? dinv_bu : dinv_td;
    const float* bias = br ? b_bu : b_td;
    const ushort* pool = linS2 + (size_t)pair * POOL_STRIDE;
    ushort* opool      = h1s2 + (size_t)pair * POOL_STRIDE;

    int tid = threadIdx.x;
    int lane = tid & 63, w = tid >> 6;
    int half = lane & 1, es = (lane >> 1) & 7, nj = lane >> 4;
    int wq = chunk * 4 + w;
    const int WPP = AGG_CHUNK * 4;
    int beg = (int)(((long long)wq * N_GROUPS) / WPP);
    int end = (int)(((long long)(wq + 1) * N_GROUPS) / WPP);
    float bs[8];
#pragma unroll
    for (int j = 0; j < 8; j++) bs[j] = bias[s * 16 + half * 8 + j];

    for (int gi = beg; gi < end; ++gi) {
        int n = gi * 4 + nj;
        int kb = off[n], ke = kb + deg[n];
        float a[8] = {0.f, 0.f, 0.f, 0.f, 0.f, 0.f, 0.f, 0.f};
        for (int k = kb + es; k < ke; k += 8) {
            int e = csr[k];
            uint4 v = *(const uint4*)(pool + (size_t)e * 16 + half * 8);
            acc8(a, v);
        }
#pragma unroll
        for (int st = 2; st <= 8; st <<= 1)
#pragma unroll
            for (int u = 0; u < 8; u++) a[u] += __shfl_xor(a[u], st);
        if (es == 0) {
            uint4 vs = *(const uint4*)(pool + (size_t)n * 16 + half * 8);  // self
            acc8(a, vs);
            float dn = dinv[n];
            float o[8];
#pragma unroll
            for (int u = 0; u < 8; u++) o[u] = fmaxf(a[u] * dn + bs[u], 0.f) * dn;
            uint4 pk;
            pk.x = (uint)f2bf(o[0]) | ((uint)f2bf(o[1]) << 16);
            pk.y = (uint)f2bf(o[2]) | ((uint)f2bf(o[3]) << 16);
            pk.z = (uint)f2bf(o[4]) | ((uint)f2bf(o[5]) << 16);
            pk.w = (uint)f2bf(o[6]) | ((uint)f2bf(o[7]) << 16);
            *(uint4*)(opool + (size_t)n * 16 + half * 8) = pk;
        }
    }
}

// ---------------------------------------------------------------------------
// Layer-2 + pool, sliced. Same structure; per-lane register accumulation per
// graph (batch sorted), flush via f32 global atomics (same-XCD blocks).
__global__ __launch_bounds__(256, 8) void agg2s_kernel(
        const ushort* __restrict__ h1s2, float* __restrict__ pooled_pre,
        const int* __restrict__ batch,
        const ushort* __restrict__ csr_td, const int* __restrict__ off_td,
        const ushort* __restrict__ deg_td, const float* __restrict__ dinv_td,
        const ushort* __restrict__ csr_bu, const int* __restrict__ off_bu,
        const ushort* __restrict__ deg_bu, const float* __restrict__ dinv_bu) {
    int b = blockIdx.x;
    int pair = b & 15;
    int chunk = b >> 4;
    int br = pair >> 3, s = pair & 7;
    const ushort* csr = br ? csr_bu : csr_td;
    const int* off    = br ? off_bu : off_td;
    const ushort* deg = br ? deg_bu : deg_td;
    const float* dinv = br ? dinv_bu : dinv_td;
    const ushort* pool = h1s2 + (size_t)pair * POOL_STRIDE;

    int tid = threadIdx.x;
    int lane = tid & 63, w = tid >> 6;
    int half = lane & 1, es = (lane >> 1) & 7, nj = lane >> 4;
    int wq = chunk * 4 + w;
    const int WPP = AGG_CHUNK * 4;
    int beg = (int)(((long long)wq * N_GROUPS) / WPP);
    int end = (int)(((long long)(wq + 1) * N_GROUPS) / WPP);

    float acc[8] = {0.f, 0.f, 0.f, 0.f, 0.f, 0.f, 0.f, 0.f};
    int gcur = -1;
    int colbase = br * F_H + s * 16 + half * 8;

    for (int gi = beg; gi < end; ++gi) {
        int n = gi * 4 + nj;
        int kb = off[n], ke = kb + deg[n];
        float a[8] = {0.f, 0.f, 0.f, 0.f, 0.f, 0.f, 0.f, 0.f};
        for (int k = kb + es; k < ke; k += 8) {
            int e = csr[k];
            uint4 v = *(const uint4*)(pool + (size_t)e * 16 + half * 8);
            acc8(a, v);
        }
#pragma unroll
        for (int st = 2; st <= 8; st <<= 1)
#pragma unroll
            for (int u = 0; u < 8; u++) a[u] += __shfl_xor(a[u], st);
        if (es == 0) {
            uint4 vs = *(const uint4*)(pool + (size_t)n * 16 + half * 8);  // self
            acc8(a, vs);
            float dn = dinv[n];
            int g = batch[n];
            if (g != gcur) {
                if (gcur >= 0) {
                    float* pp = &pooled_pre[(size_t)gcur * F_CAT + colbase];
#pragma unroll
                    for (int u = 0; u < 8; u++) unsafeAtomicAdd(pp + u, acc[u]);
                }
                gcur = g;
#pragma unroll
                for (int u = 0; u < 8; u++) acc[u] = 0.f;
            }
#pragma unroll
            for (int u = 0; u < 8; u++) acc[u] += a[u] * dn;
        }
    }
    if (es == 0 && gcur >= 0) {
        float* pp = &pooled_pre[(size_t)gcur * F_CAT + colbase];
#pragma unroll
        for (int u = 0; u < 8; u++) unsafeAtomicAdd(pp + u, acc[u]);
    }
}

// ---------------------------------------------------------------------------
// Head: z = pooled_pre @ W2 (per branch) + cnt*b2 in concat([bu,td]) order,
// then MLP relu(z@pw1+pb1)@pw2+pb2. One block per graph.
__global__ __launch_bounds__(256) void head_kernel(
        const float* __restrict__ pooled_pre, const int* __restrict__ batch,
        const ushort* __restrict__ Wt2,
        const float* __restrict__ td_b2, const float* __restrict__ bu_b2,
        const float* __restrict__ pw1, const float* __restrict__ pb1,
        const float* __restrict__ pw2, const float* __restrict__ pb2,
        float* __restrict__ out) {
    int g = blockIdx.x;
    int tid = threadIdx.x;
    __shared__ float row[256], z[256], hid[256];
    row[tid] = pooled_pre[(size_t)g * 256 + tid];
    int lo = 0, hi = N_NODES;
    while (lo < hi) { int m = (lo + hi) >> 1; if (batch[m] < g) lo = m + 1; else hi = m; }
    int start = lo;
    lo = start; hi = N_NODES;
    while (lo < hi) { int m = (lo + hi) >> 1; if (batch[m] < g + 1) lo = m + 1; else hi = m; }
    float cnt = (float)(lo - start);
    __syncthreads();
    const float* rsel = (tid < 128) ? (row + F_H) : row;
    float b2 = (tid < 128) ? bu_b2[tid] : td_b2[tid - F_H];
    float acc = cnt * b2;
    for (int k = 0; k < F_H; k++) acc += rsel[k] * bfu(Wt2[(size_t)k * 256 + tid]);
    z[tid] = acc;
    __syncthreads();
    float h = pb1[tid];
    for (int k = 0; k < 256; k++) h += z[k] * pw1[(size_t)k * 256 + tid];
    hid[tid] = fmaxf(h, 0.f);
    __syncthreads();
    if (tid < 128) {
        float o = pb2[tid];
        for (int k = 0; k < 256; k++) o += hid[k] * pw2[(size_t)k * 128 + tid];
        out[(size_t)g * 128 + tid] = o;
    }
}

// ---------------------------------------------------------------------------
extern "C" void kernel_launch(void* const* d_in, const int* in_sizes, int n_in,
                              void* d_out, int out_size, void* d_ws, size_t ws_size,
                              hipStream_t stream) {
    const float* x     = (const float*)d_in[0];
    const int*   ei    = (const int*)d_in[1];
    const int*   batch = (const int*)d_in[2];
    const float* td_W1 = (const float*)d_in[4];
    const float* td_b1 = (const float*)d_in[5];
    const float* td_W2 = (const float*)d_in[6];
    const float* td_b2 = (const float*)d_in[7];
    const float* bu_W1 = (const float*)d_in[8];
    const float* bu_b1 = (const float*)d_in[9];
    const float* bu_W2 = (const float*)d_in[10];
    const float* bu_b2 = (const float*)d_in[11];
    const float* pw1   = (const float*)d_in[12];
    const float* pb1   = (const float*)d_in[13];
    const float* pw2   = (const float*)d_in[14];
    const float* pb2   = (const float*)d_in[15];
    float* out = (float*)d_out;

    // ---- workspace carve ----
    char* p = (char*)d_ws;
    auto alloc = [&](size_t bytes) { void* r = (void*)p; p += (bytes + 255) & ~(size_t)255; return r; };
    // single memset region: gcur (1 KB) + pooled_pre (512 KB)
    char* zreg = (char*)alloc(1024 + (size_t)N_GRAPHS * F_CAT * sizeof(float));
    int* gcur = (int*)zreg;
    float* pooled_pre = (float*)(zreg + 1024);
    uint* ebuf_td = (uint*)alloc((size_t)NB * CAP * sizeof(uint));
    uint* ebuf_bu = (uint*)alloc((size_t)NB * CAP * sizeof(uint));
    ushort* csr_td = (ushort*)alloc((size_t)NB * CAP * sizeof(ushort));
    ushort* csr_bu = (ushort*)alloc((size_t)NB * CAP * sizeof(ushort));
    int* off_td = (int*)alloc((size_t)N_NODES * sizeof(int));
    int* off_bu = (int*)alloc((size_t)N_NODES * sizeof(int));
    ushort* deg_td = (ushort*)alloc((size_t)N_NODES * sizeof(ushort));
    ushort* deg_bu = (ushort*)alloc((size_t)N_NODES * sizeof(ushort));
    float* dinv_td = (float*)alloc((size_t)N_PAD * sizeof(float));
    float* dinv_bu = (float*)alloc((size_t)N_PAD * sizeof(float));
    ushort* Bt1 = (ushort*)alloc((size_t)256 * 256 * sizeof(ushort));
    ushort* Wt2 = (ushort*)alloc((size_t)128 * 256 * sizeof(ushort));
    ushort* linb = (ushort*)alloc((size_t)NPAIR * POOL_STRIDE * sizeof(ushort));
    ushort* h1s  = (ushort*)alloc((size_t)NPAIR * POOL_STRIDE * sizeof(ushort));

    hipMemsetAsync(zreg, 0, 1024 + (size_t)N_GRAPHS * F_CAT * sizeof(float), stream);

    // ---- weights prep ----
    prep_w_kernel<<<256, 256, 0, stream>>>(td_W1, bu_W1, td_W2, bu_W2, Bt1, Wt2);

    // ---- graph structure (bucketed counting sort; csr_build emits dinv) ----
    csr_scatter_kernel<<<N_EDGES / EPB, 256, 0, stream>>>(ei, gcur, ebuf_td, ebuf_bu);
    csr_build_kernel<<<dim3(NB, 2), 256, 0, stream>>>(ebuf_td, ebuf_bu, gcur,
        off_td, off_bu, deg_td, deg_bu, dinv_td, dinv_bu, csr_td, csr_bu);

    // ---- layer 1: GEMM (slice-major output; dinv folded) ----
    dim3 gg(N_PAD / 128, 2);
    gemm_mfma<<<gg, 256, 0, stream>>>(x, Bt1, linb, dinv_td, dinv_bu);
    agg1s_kernel<<<NPAIR * AGG_CHUNK, 256, 0, stream>>>(linb, h1s,
        csr_td, off_td, deg_td, dinv_td, csr_bu, off_bu, deg_bu, dinv_bu, td_b1, bu_b1);

    // ---- layer 2 + pool: sliced, XCD-local gather ----
    agg2s_kernel<<<NPAIR * AGG_CHUNK, 256, 0, stream>>>(h1s, pooled_pre, batch,
        csr_td, off_td, deg_td, dinv_td, csr_bu, off_bu, deg_bu, dinv_bu);

    // ---- head: W2 matvec + cnt*b2 + MLP ----
    head_kernel<<<N_GRAPHS, 256, 0, stream>>>(pooled_pre, batch, Wt2,
        td_b2, bu_b2, pw1, pb1, pw2, pb2, out);
}